// Round 17
// baseline (99.162 us; speedup 1.0000x reference)
//
#include <hip/hip_runtime.h>
#include <hip/hip_bf16.h>
#include <stdint.h>

// Q8_0 dequant linear: y = x @ W^T + bias.  M=N=K=4096.
// INT8 path, 32x32x32 MFMA variant of the session-best r7 schedule:
// same 256x256 tile, BKB=128, same staging/swizzle/sync (4 phases, 1
// barrier/phase, counted vmcnt, XOR-swizzled LDS), but
// mfma_i32_32x32x32_i8 (4404 TOPS ubench vs 3944 for 16x16x64; half the
// instruction count). Epilogue uses the verified 32x32 C/D mapping
// col=lane&31, row=(r&3)+8*(r>>2)+4*(lane>>5).

#define M_DIM 4096
#define N_DIM 4096
#define K_DIM 4096
#define NB_SC 128

#define BM 256
#define BN 256
#define BKB 128                  // K-tile in bytes (= elements, i8)
#define NT (K_DIM / BKB)         // 32 K-tiles
#define TILE_B (BM * BKB)        // 32 KiB per tile buffer

typedef __attribute__((ext_vector_type(4))) int i32x4;
typedef __attribute__((ext_vector_type(16))) int i32x16;

__device__ __forceinline__ void gload_lds16(const void* gsrc, void* ldsdst) {
  __builtin_amdgcn_global_load_lds(
      (__attribute__((address_space(1))) void*)(uintptr_t)gsrc,
      (__attribute__((address_space(3))) void*)(uint32_t)(uintptr_t)ldsdst,
      16, 0, 0);
}

__device__ __forceinline__ int pack4(int a, int b, int c, int d) {
  return (a & 255) | ((b & 255) << 8) | ((c & 255) << 16) | ((d & 255) << 24);
}

// ---------------- fused prep kernel (unchanged, verified) ----------------

__global__ void prep_kernel(const float* __restrict__ x, const int* __restrict__ q,
                            const float* __restrict__ sc,
                            char* __restrict__ xb, char* __restrict__ wb,
                            float* __restrict__ sxv, float* __restrict__ swv) {
  __shared__ float red[4];
  const int b = blockIdx.x;
  const int t = threadIdx.x;
  if (b < 4096) {
    const float4* row = (const float4*)(x + (size_t)b * K_DIM);
    float4 v[4];
    float m = 0.f;
#pragma unroll
    for (int i = 0; i < 4; ++i) {
      v[i] = row[t * 4 + i];
      m = fmaxf(m, fmaxf(fmaxf(fabsf(v[i].x), fabsf(v[i].y)),
                         fmaxf(fabsf(v[i].z), fabsf(v[i].w))));
    }
#pragma unroll
    for (int off = 32; off >= 1; off >>= 1) m = fmaxf(m, __shfl_xor(m, off, 64));
    if ((t & 63) == 0) red[t >> 6] = m;
    __syncthreads();
    m = fmaxf(fmaxf(red[0], red[1]), fmaxf(red[2], red[3]));
    const float inv = (m > 0.f) ? 127.0f / m : 0.f;
    int4 o;
    o.x = pack4(__float2int_rn(v[0].x * inv), __float2int_rn(v[0].y * inv),
                __float2int_rn(v[0].z * inv), __float2int_rn(v[0].w * inv));
    o.y = pack4(__float2int_rn(v[1].x * inv), __float2int_rn(v[1].y * inv),
                __float2int_rn(v[1].z * inv), __float2int_rn(v[1].w * inv));
    o.z = pack4(__float2int_rn(v[2].x * inv), __float2int_rn(v[2].y * inv),
                __float2int_rn(v[2].z * inv), __float2int_rn(v[2].w * inv));
    o.w = pack4(__float2int_rn(v[3].x * inv), __float2int_rn(v[3].y * inv),
                __float2int_rn(v[3].z * inv), __float2int_rn(v[3].w * inv));
    ((int4*)(xb + (size_t)b * K_DIM))[t] = o;
    if (t == 0) sxv[b] = m / 127.0f;
  } else {
    const int o_row = b - 4096;
    float m = sc[o_row * NB_SC + (t & 127)];
#pragma unroll
    for (int off = 32; off >= 1; off >>= 1) m = fmaxf(m, __shfl_xor(m, off, 64));
    if ((t & 63) == 0) red[t >> 6] = m;
    __syncthreads();
    m = fmaxf(fmaxf(red[0], red[1]), fmaxf(red[2], red[3]));
    const float ratio = sc[o_row * NB_SC + (t >> 1)] / m;   // scales >= 1e-4 > 0
    const int4* qp = (const int4*)(q + (size_t)o_row * K_DIM);
    int4 qv[4];
#pragma unroll
    for (int i = 0; i < 4; ++i) qv[i] = qp[t * 4 + i];
    int4 ov;
    ov.x = pack4(__float2int_rn((float)qv[0].x * ratio), __float2int_rn((float)qv[0].y * ratio),
                 __float2int_rn((float)qv[0].z * ratio), __float2int_rn((float)qv[0].w * ratio));
    ov.y = pack4(__float2int_rn((float)qv[1].x * ratio), __float2int_rn((float)qv[1].y * ratio),
                 __float2int_rn((float)qv[1].z * ratio), __float2int_rn((float)qv[1].w * ratio));
    ov.z = pack4(__float2int_rn((float)qv[2].x * ratio), __float2int_rn((float)qv[2].y * ratio),
                 __float2int_rn((float)qv[2].z * ratio), __float2int_rn((float)qv[2].w * ratio));
    ov.w = pack4(__float2int_rn((float)qv[3].x * ratio), __float2int_rn((float)qv[3].y * ratio),
                 __float2int_rn((float)qv[3].z * ratio), __float2int_rn((float)qv[3].w * ratio));
    ((int4*)(wb + (size_t)o_row * K_DIM))[t] = ov;
    if (t == 0) swv[o_row] = m;
  }
}

// ---------------- 256x256 BK=128 i8 GEMM (32x32x32 MFMA) ----------------
// LDS tile [256][128] i8, 128B rows = 8 x 16B granules. Logical granule g of
// row r stored at granule g^(r&7); gload_lds dest linear, source pre-permuted.

__device__ __forceinline__ i32x4 lds_frag(const char* t, int r, int kb) {
  return *(const i32x4*)(t + r * BKB + ((((kb) >> 4) ^ (r & 7)) << 4));
}

__device__ __forceinline__ void stage_half(const char* __restrict__ pX,
                                           char* lds, int hr0, int ktb, int w) {
#pragma unroll
  for (int j = 0; j < 2; ++j) {
    gload_lds16(pX + (size_t)(hr0 + j * 8) * K_DIM + ktb,
                lds + (hr0 + w * 16 + j * 8) * BKB);
  }
}

// A frags for one kstep: 4 M-subtiles (rows wm*128 + mt*32 + (l&31))
__device__ __forceinline__ void read_aks(const char* Ac, int wm, int l31, int kb,
                                         i32x4 (&af)[4]) {
#pragma unroll
  for (int mt = 0; mt < 4; ++mt)
    af[mt] = lds_frag(Ac, wm * 128 + mt * 32 + l31, kb);
}

// All B frags of a tile: 2 N-subtiles x 4 ksteps
__device__ __forceinline__ void read_ball(const char* Bc, int wn, int l31, int kbb,
                                          i32x4 (&bf)[2][4]) {
#pragma unroll
  for (int nt = 0; nt < 2; ++nt)
#pragma unroll
    for (int ks = 0; ks < 4; ++ks)
      bf[nt][ks] = lds_frag(Bc, wn * 64 + nt * 32 + l31, kbb + ks * 32);
}

template <int KS>
__device__ __forceinline__ void mfma_ks(const i32x4 (&af)[4], const i32x4 (&bf)[2][4],
                                        i32x16 (&acc)[4][2]) {
  __builtin_amdgcn_s_setprio(1);
#pragma unroll
  for (int mt = 0; mt < 4; ++mt)
#pragma unroll
    for (int nt = 0; nt < 2; ++nt)
      acc[mt][nt] =
          __builtin_amdgcn_mfma_i32_32x32x32_i8(af[mt], bf[nt][KS], acc[mt][nt], 0, 0, 0);
  __builtin_amdgcn_s_setprio(0);
}

// MODE: 0 = steady; 1 = t == NT-2 (A(t+1) stage only, vmcnt(0)); 2 = last tile
// Entering: bf_cur holds all B frags of tile t; a0_cur holds kstep-0 A frags.
template <int BUF, int MODE>
__device__ __forceinline__ void ktile(const char* __restrict__ pA,
                                      const char* __restrict__ pB,
                                      char* AsB, char* BsB,
                                      int ktb, int w, int wm, int wn, int l31, int kbb,
                                      i32x16 (&acc)[4][2],
                                      i32x4 (&bf_cur)[2][4], i32x4 (&bf_nxt)[2][4],
                                      i32x4 (&a0_cur)[4], i32x4 (&a0_nxt)[4]) {
  const char* Ac = AsB + BUF * TILE_B;
  const char* An = AsB + (BUF ^ 1) * TILE_B;
  const char* Bn = BsB + (BUF ^ 1) * TILE_B;
  char* Anw = AsB + (BUF ^ 1) * TILE_B;
  char* Bw  = BsB + BUF * TILE_B;

  i32x4 a1[4], a2[4], a3[4];

  // p0: read A ks1; stage A0+A1(t+1)->other buf; MFMA ks0
  read_aks(Ac, wm, l31, kbb + 32, a1);
  if (MODE < 2) {
    stage_half(pA, Anw, 0, ktb + BKB, w);
    stage_half(pA, Anw, 128, ktb + BKB, w);
  }
  __builtin_amdgcn_sched_barrier(0);
  mfma_ks<0>(a0_cur, bf_cur, acc);
  __builtin_amdgcn_s_barrier();

  // p1: read A ks2; stage B0(t+2)->cur buf; MFMA ks1
  read_aks(Ac, wm, l31, kbb + 64, a2);
  if (MODE == 0) stage_half(pB, Bw, 0, ktb + 2 * BKB, w);
  __builtin_amdgcn_sched_barrier(0);
  mfma_ks<1>(a1, bf_cur, acc);
  __builtin_amdgcn_s_barrier();

  // p2: read A ks3; stage B1(t+2); MFMA ks2
  read_aks(Ac, wm, l31, kbb + 96, a3);
  if (MODE == 0) stage_half(pB, Bw, 128, ktb + 2 * BKB, w);
  __builtin_amdgcn_sched_barrier(0);
  mfma_ks<2>(a2, bf_cur, acc);
  __builtin_amdgcn_s_barrier();

  // p3: counted vmcnt (drains B(t+1)+A(t+1), leaves B(t+2) in flight);
  // read next tile's B frags + kstep-0 A; MFMA ks3
  if (MODE == 0)
    asm volatile("s_waitcnt vmcnt(4)" ::: "memory");
  else if (MODE == 1)
    asm volatile("s_waitcnt vmcnt(0)" ::: "memory");
  if (MODE < 2) {
    read_ball(Bn, wn, l31, kbb, bf_nxt);
    read_aks(An, wm, l31, kbb, a0_nxt);
  }
  __builtin_amdgcn_sched_barrier(0);
  mfma_ks<3>(a3, bf_cur, acc);
  __builtin_amdgcn_s_barrier();
}

__global__ __launch_bounds__(512, 2) void gemm256(const char* __restrict__ A,
                                                  const char* __restrict__ B,
                                                  const float* __restrict__ sxv,
                                                  const float* __restrict__ swv,
                                                  const float* __restrict__ bias,
                                                  float* __restrict__ C) {
  __shared__ char AsB[2 * TILE_B];   // 64 KiB
  __shared__ char BsB[2 * TILE_B];   // 64 KiB

  const int tid = threadIdx.x;
  const int w = tid >> 6;
  const int l = tid & 63;
  const int wm = w >> 2;
  const int wn = w & 3;
  const int l31 = l & 31;
  const int kbb = (l >> 5) * 16;     // byte offset of lane's 16-i8 k-slice

  const int bid = blockIdx.x;
  const int cpx = gridDim.x >> 3;
  const int swz = (bid & 7) * cpx + (bid >> 3);
  const int bm0 = (swz >> 4) * BM;
  const int bn0 = (swz & 15) * BN;

  // lane-constant stage base pointers (pre-swizzled source granule)
  const int sr = l >> 3;
  const int skp = ((l & 7) ^ sr) << 4;
  const char* pA = A + (size_t)(bm0 + w * 16 + sr) * K_DIM + skp;
  const char* pB = B + (size_t)(bn0 + w * 16 + sr) * K_DIM + skp;

  i32x16 acc[4][2] = {};
  i32x4 bf0[2][4], bf1[2][4];
  i32x4 a00[4], a01[4];

  // Prologue: tile0 {B0,B1,A0,A1}, then B0,B1(tile1). vmcnt(4): tile0 landed.
  stage_half(pB, BsB, 0, 0, w);
  stage_half(pB, BsB, 128, 0, w);
  stage_half(pA, AsB, 0, 0, w);
  stage_half(pA, AsB, 128, 0, w);
  stage_half(pB, BsB + TILE_B, 0, BKB, w);
  stage_half(pB, BsB + TILE_B, 128, BKB, w);
  asm volatile("s_waitcnt vmcnt(4)" ::: "memory");
  __builtin_amdgcn_s_barrier();
  read_ball(BsB, wn, l31, kbb, bf0);
  read_aks(AsB, wm, l31, kbb, a00);

  for (int t = 0; t < NT - 2; t += 2) {
    ktile<0, 0>(pA, pB, AsB, BsB, t * BKB, w, wm, wn, l31, kbb, acc, bf0, bf1, a00, a01);
    ktile<1, 0>(pA, pB, AsB, BsB, (t + 1) * BKB, w, wm, wn, l31, kbb, acc, bf1, bf0, a01, a00);
  }
  ktile<0, 1>(pA, pB, AsB, BsB, (NT - 2) * BKB, w, wm, wn, l31, kbb, acc, bf0, bf1, a00, a01);
  ktile<1, 2>(pA, pB, AsB, BsB, (NT - 1) * BKB, w, wm, wn, l31, kbb, acc, bf1, bf0, a01, a00);

  // Epilogue: y = s_x[m]*s_w[n]*acc + bias[n]
  // 32x32 C/D: col = lane&31, row = (r&3) + 8*(r>>2) + 4*(lane>>5)
#pragma unroll
  for (int nt = 0; nt < 2; ++nt) {
    const int n = bn0 + wn * 64 + nt * 32 + l31;
    const float swn = swv[n];
    const float bv = bias[n];
#pragma unroll
    for (int mt = 0; mt < 4; ++mt) {
      const int mbase = bm0 + wm * 128 + mt * 32 + (l >> 5) * 4;
#pragma unroll
      for (int r = 0; r < 16; ++r) {
        const int m = mbase + (r & 3) + 8 * (r >> 2);
        C[(size_t)m * N_DIM + n] = (float)acc[mt][nt][r] * (swn * sxv[m]) + bv;
      }
    }
  }
}

// ---------------- naive fallback ----------------

__global__ void naive_kernel(const float* __restrict__ x, const int* __restrict__ q,
                             const float* __restrict__ sc, const float* __restrict__ bias,
                             float* __restrict__ out) {
  size_t idx = (size_t)blockIdx.x * blockDim.x + threadIdx.x;
  if (idx >= (size_t)M_DIM * N_DIM) return;
  int n = (int)(idx & (N_DIM - 1));
  size_t m = idx >> 12;
  float acc = 0.f;
  for (int k = 0; k < K_DIM; k += 32) {
    float s = sc[n * NB_SC + (k >> 5)];
    float part = 0.f;
    for (int j = 0; j < 32; ++j)
      part += x[m * K_DIM + k + j] * (float)q[(size_t)n * K_DIM + k + j];
    acc += part * s;
  }
  out[idx] = acc + bias[n];
}

// ---------------- launch ----------------

extern "C" void kernel_launch(void* const* d_in, const int* in_sizes, int n_in,
                              void* d_out, int out_size, void* d_ws, size_t ws_size,
                              hipStream_t stream) {
  const float* x    = (const float*)d_in[0];
  const int*   q    = (const int*)d_in[1];
  const float* sc   = (const float*)d_in[2];
  const float* bias = (const float*)d_in[3];
  float* out = (float*)d_out;

  const size_t elems = (size_t)M_DIM * K_DIM;
  const size_t need  = 2 * elems + 2 * 4096 * sizeof(float);

  if (ws_size >= need) {
    char* xb = (char*)d_ws;
    char* wb = xb + elems;
    float* sxv = (float*)(wb + elems);
    float* swv = sxv + 4096;
    hipLaunchKernelGGL(prep_kernel, dim3(8192), dim3(256), 0, stream,
                       x, q, sc, xb, wb, sxv, swv);
    hipLaunchKernelGGL(gemm256, dim3((M_DIM / BM) * (N_DIM / BN)), dim3(512), 0, stream,
                       xb, wb, sxv, swv, bias, out);
  } else {
    hipLaunchKernelGGL(naive_kernel, dim3((M_DIM * N_DIM) / 256), dim3(256), 0, stream,
                       x, q, sc, bias, out);
  }
}

// Round 18
// 91.429 us; speedup vs baseline: 1.0846x; 1.0846x over previous
//
#include <hip/hip_runtime.h>
#include <hip/hip_bf16.h>
#include <stdint.h>

// Q8_0 dequant linear: y = x @ W^T + bias.  M=N=K=4096.
// INT8 path (session best, reproduced 3x: ~91 us total, GEMM ~70 us,
// absmax 3.5 vs threshold 6.16): prep quantizes x per-row to i8 (s_x) and
// requantizes W per-row (s_w = max block scale); 256x256-tile BK=128 i8
// MFMA GEMM (mfma_i32_16x16x64_i8), 4 phases/K-tile, 1 barrier/phase,
// reads-one-quad-ahead, sched_barrier, counted vmcnt, XOR-swizzled LDS
// (0 conflicts); epilogue y = s_x[m]*s_w[n]*acc + bias[n].

#define M_DIM 4096
#define N_DIM 4096
#define K_DIM 4096
#define NB_SC 128

#define BM 256
#define BN 256
#define BKB 128                  // K-tile in bytes (= elements, i8)
#define NT (K_DIM / BKB)         // 32 K-tiles
#define TILE_B (BM * BKB)        // 32 KiB per tile buffer

typedef __attribute__((ext_vector_type(4))) int i32x4;

__device__ __forceinline__ void gload_lds16(const void* gsrc, void* ldsdst) {
  __builtin_amdgcn_global_load_lds(
      (__attribute__((address_space(1))) void*)(uintptr_t)gsrc,
      (__attribute__((address_space(3))) void*)(uint32_t)(uintptr_t)ldsdst,
      16, 0, 0);
}

__device__ __forceinline__ int pack4(int a, int b, int c, int d) {
  return (a & 255) | ((b & 255) << 8) | ((c & 255) << 16) | ((d & 255) << 24);
}

// ---------------- fused prep kernel ----------------
// blocks [0,4096): quantize x row b;  blocks [4096,8192): requantize W row b-4096.

__global__ void prep_kernel(const float* __restrict__ x, const int* __restrict__ q,
                            const float* __restrict__ sc,
                            char* __restrict__ xb, char* __restrict__ wb,
                            float* __restrict__ sxv, float* __restrict__ swv) {
  __shared__ float red[4];
  const int b = blockIdx.x;
  const int t = threadIdx.x;
  if (b < 4096) {
    const float4* row = (const float4*)(x + (size_t)b * K_DIM);
    float4 v[4];
    float m = 0.f;
#pragma unroll
    for (int i = 0; i < 4; ++i) {
      v[i] = row[t * 4 + i];
      m = fmaxf(m, fmaxf(fmaxf(fabsf(v[i].x), fabsf(v[i].y)),
                         fmaxf(fabsf(v[i].z), fabsf(v[i].w))));
    }
#pragma unroll
    for (int off = 32; off >= 1; off >>= 1) m = fmaxf(m, __shfl_xor(m, off, 64));
    if ((t & 63) == 0) red[t >> 6] = m;
    __syncthreads();
    m = fmaxf(fmaxf(red[0], red[1]), fmaxf(red[2], red[3]));
    const float inv = (m > 0.f) ? 127.0f / m : 0.f;
    int4 o;
    o.x = pack4(__float2int_rn(v[0].x * inv), __float2int_rn(v[0].y * inv),
                __float2int_rn(v[0].z * inv), __float2int_rn(v[0].w * inv));
    o.y = pack4(__float2int_rn(v[1].x * inv), __float2int_rn(v[1].y * inv),
                __float2int_rn(v[1].z * inv), __float2int_rn(v[1].w * inv));
    o.z = pack4(__float2int_rn(v[2].x * inv), __float2int_rn(v[2].y * inv),
                __float2int_rn(v[2].z * inv), __float2int_rn(v[2].w * inv));
    o.w = pack4(__float2int_rn(v[3].x * inv), __float2int_rn(v[3].y * inv),
                __float2int_rn(v[3].z * inv), __float2int_rn(v[3].w * inv));
    ((int4*)(xb + (size_t)b * K_DIM))[t] = o;
    if (t == 0) sxv[b] = m / 127.0f;
  } else {
    const int o_row = b - 4096;
    float m = sc[o_row * NB_SC + (t & 127)];
#pragma unroll
    for (int off = 32; off >= 1; off >>= 1) m = fmaxf(m, __shfl_xor(m, off, 64));
    if ((t & 63) == 0) red[t >> 6] = m;
    __syncthreads();
    m = fmaxf(fmaxf(red[0], red[1]), fmaxf(red[2], red[3]));
    const float ratio = sc[o_row * NB_SC + (t >> 1)] / m;   // scales >= 1e-4 > 0
    const int4* qp = (const int4*)(q + (size_t)o_row * K_DIM);
    int4 qv[4];
#pragma unroll
    for (int i = 0; i < 4; ++i) qv[i] = qp[t * 4 + i];
    int4 ov;
    ov.x = pack4(__float2int_rn((float)qv[0].x * ratio), __float2int_rn((float)qv[0].y * ratio),
                 __float2int_rn((float)qv[0].z * ratio), __float2int_rn((float)qv[0].w * ratio));
    ov.y = pack4(__float2int_rn((float)qv[1].x * ratio), __float2int_rn((float)qv[1].y * ratio),
                 __float2int_rn((float)qv[1].z * ratio), __float2int_rn((float)qv[1].w * ratio));
    ov.z = pack4(__float2int_rn((float)qv[2].x * ratio), __float2int_rn((float)qv[2].y * ratio),
                 __float2int_rn((float)qv[2].z * ratio), __float2int_rn((float)qv[2].w * ratio));
    ov.w = pack4(__float2int_rn((float)qv[3].x * ratio), __float2int_rn((float)qv[3].y * ratio),
                 __float2int_rn((float)qv[3].z * ratio), __float2int_rn((float)qv[3].w * ratio));
    ((int4*)(wb + (size_t)o_row * K_DIM))[t] = ov;
    if (t == 0) swv[o_row] = m;
  }
}

// ---------------- 256x256 BK=128 i8 GEMM ----------------
// LDS tile [256][128] i8, 128B rows = 8 x 16B granules. Logical granule g of
// row r stored at granule g^(r&7); gload_lds dest linear, source pre-permuted.

__device__ __forceinline__ i32x4 lds_frag(const char* t, int r, int kb) {
  return *(const i32x4*)(t + r * BKB + ((((kb) >> 4) ^ (r & 7)) << 4));
}

__device__ __forceinline__ void stage_half(const char* __restrict__ pX,
                                           char* lds, int hr0, int ktb, int w) {
#pragma unroll
  for (int j = 0; j < 2; ++j) {
    gload_lds16(pX + (size_t)(hr0 + j * 8) * K_DIM + ktb,
                lds + (hr0 + w * 16 + j * 8) * BKB);
  }
}

__device__ __forceinline__ void read_a(const char* Ac, int r0, int frow, int fkb,
                                       i32x4 (&af)[2][2]) {
#pragma unroll
  for (int q = 0; q < 2; ++q)
#pragma unroll
    for (int kk = 0; kk < 2; ++kk)
      af[q][kk] = lds_frag(Ac, r0 + q * 16 + frow, kk * 64 + fkb);
}

__device__ __forceinline__ void read_b(const char* Bc, int wn, int frow, int fkb,
                                       i32x4 (&bf)[4][2]) {
#pragma unroll
  for (int ni = 0; ni < 4; ++ni)
#pragma unroll
    for (int kk = 0; kk < 2; ++kk)
      bf[ni][kk] = lds_frag(Bc, wn * 64 + ni * 16 + frow, kk * 64 + fkb);
}

__device__ __forceinline__ void mfma_quad(const i32x4 (&af)[2][2], const i32x4 (&bf)[4][2],
                                          i32x4 (&acc)[8][4], int q0) {
  __builtin_amdgcn_s_setprio(1);
#pragma unroll
  for (int q = 0; q < 2; ++q)
#pragma unroll
    for (int ni = 0; ni < 4; ++ni)
#pragma unroll
      for (int kk = 0; kk < 2; ++kk)
        acc[q0 + q][ni] =
            __builtin_amdgcn_mfma_i32_16x16x64_i8(af[q][kk], bf[ni][kk], acc[q0 + q][ni], 0, 0, 0);
  __builtin_amdgcn_s_setprio(0);
}

// MODE: 0 = steady; 1 = t == NT-2 (A(t+1) stage only, vmcnt(0)); 2 = last tile
// Entering: bf_cur/a0_cur hold tile t's B-frags and quad-0 (issued last phase).
template <int BUF, int MODE>
__device__ __forceinline__ void ktile(const char* __restrict__ pA,
                                      const char* __restrict__ pB,
                                      char* AsB, char* BsB,
                                      int ktb, int w, int wm, int wn, int frow, int fkb,
                                      i32x4 (&acc)[8][4],
                                      i32x4 (&bf_cur)[4][2], i32x4 (&bf_nxt)[4][2],
                                      i32x4 (&a0_cur)[2][2], i32x4 (&a0_nxt)[2][2]) {
  const char* Ac = AsB + BUF * TILE_B;
  const char* An = AsB + (BUF ^ 1) * TILE_B;
  const char* Bn = BsB + (BUF ^ 1) * TILE_B;
  char* Anw = AsB + (BUF ^ 1) * TILE_B;
  char* Bw  = BsB + BUF * TILE_B;

  i32x4 a1[2][2], a2[2][2], a3[2][2];

  // p0: reads a1(t); stage A0+A1(t+1)->other buf; MFMA q0 (a1 stays in flight)
  read_a(Ac, wm * 128 + 32, frow, fkb, a1);
  if (MODE < 2) {
    stage_half(pA, Anw, 0, ktb + BKB, w);
    stage_half(pA, Anw, 128, ktb + BKB, w);
  }
  __builtin_amdgcn_sched_barrier(0);
  mfma_quad(a0_cur, bf_cur, acc, 0);
  __builtin_amdgcn_s_barrier();

  // p1: reads a2(t); stage B0(t+2)->cur buf; MFMA q1
  read_a(Ac, wm * 128 + 64, frow, fkb, a2);
  if (MODE == 0) stage_half(pB, Bw, 0, ktb + 2 * BKB, w);
  __builtin_amdgcn_sched_barrier(0);
  mfma_quad(a1, bf_cur, acc, 2);
  __builtin_amdgcn_s_barrier();

  // p2: reads a3(t); stage B1(t+2); MFMA q2
  read_a(Ac, wm * 128 + 96, frow, fkb, a3);
  if (MODE == 0) stage_half(pB, Bw, 128, ktb + 2 * BKB, w);
  __builtin_amdgcn_sched_barrier(0);
  mfma_quad(a2, bf_cur, acc, 4);
  __builtin_amdgcn_s_barrier();

  // p3: counted vmcnt (drains B(t+1)+A(t+1), leaves B(t+2) in flight);
  // read next tile's B-frags + quad-0; MFMA q3
  if (MODE == 0)
    asm volatile("s_waitcnt vmcnt(4)" ::: "memory");
  else if (MODE == 1)
    asm volatile("s_waitcnt vmcnt(0)" ::: "memory");
  if (MODE < 2) {
    read_b(Bn, wn, frow, fkb, bf_nxt);
    read_a(An, wm * 128 + 0, frow, fkb, a0_nxt);
  }
  __builtin_amdgcn_sched_barrier(0);
  mfma_quad(a3, bf_cur, acc, 6);
  __builtin_amdgcn_s_barrier();
}

__global__ __launch_bounds__(512, 2) void gemm256(const char* __restrict__ A,
                                                  const char* __restrict__ B,
                                                  const float* __restrict__ sxv,
                                                  const float* __restrict__ swv,
                                                  const float* __restrict__ bias,
                                                  float* __restrict__ C) {
  __shared__ char AsB[2 * TILE_B];   // 64 KiB
  __shared__ char BsB[2 * TILE_B];   // 64 KiB

  const int tid = threadIdx.x;
  const int w = tid >> 6;
  const int l = tid & 63;
  const int wm = w >> 2;
  const int wn = w & 3;
  const int frow = l & 15;
  const int fkb = (l >> 4) * 16;     // byte offset of lane's 16 i8 K-slice

  const int bid = blockIdx.x;
  const int cpx = gridDim.x >> 3;
  const int swz = (bid & 7) * cpx + (bid >> 3);
  const int bm0 = (swz >> 4) * BM;
  const int bn0 = (swz & 15) * BN;

  // lane-constant stage base pointers (pre-swizzled source granule)
  const int sr = l >> 3;
  const int skp = ((l & 7) ^ sr) << 4;
  const char* pA = A + (size_t)(bm0 + w * 16 + sr) * K_DIM + skp;
  const char* pB = B + (size_t)(bn0 + w * 16 + sr) * K_DIM + skp;

  i32x4 acc[8][4] = {};
  i32x4 bf0[4][2], bf1[4][2];
  i32x4 a00[2][2], a01[2][2];

  // Prologue: tile0 {B0,B1,A0,A1}, then B0,B1(tile1). vmcnt(4): tile0 landed.
  stage_half(pB, BsB, 0, 0, w);
  stage_half(pB, BsB, 128, 0, w);
  stage_half(pA, AsB, 0, 0, w);
  stage_half(pA, AsB, 128, 0, w);
  stage_half(pB, BsB + TILE_B, 0, BKB, w);
  stage_half(pB, BsB + TILE_B, 128, BKB, w);
  asm volatile("s_waitcnt vmcnt(4)" ::: "memory");
  __builtin_amdgcn_s_barrier();
  read_b(BsB, wn, frow, fkb, bf0);
  read_a(AsB, wm * 128 + 0, frow, fkb, a00);

  for (int t = 0; t < NT - 2; t += 2) {
    ktile<0, 0>(pA, pB, AsB, BsB, t * BKB, w, wm, wn, frow, fkb, acc, bf0, bf1, a00, a01);
    ktile<1, 0>(pA, pB, AsB, BsB, (t + 1) * BKB, w, wm, wn, frow, fkb, acc, bf1, bf0, a01, a00);
  }
  ktile<0, 1>(pA, pB, AsB, BsB, (NT - 2) * BKB, w, wm, wn, frow, fkb, acc, bf0, bf1, a00, a01);
  ktile<1, 2>(pA, pB, AsB, BsB, (NT - 1) * BKB, w, wm, wn, frow, fkb, acc, bf1, bf0, a01, a00);

  // Epilogue: y = s_x[m]*s_w[n]*acc + bias[n]; C/D col=l&15, row=(l>>4)*4+r
#pragma unroll
  for (int ni = 0; ni < 4; ++ni) {
    const int n = bn0 + wn * 64 + ni * 16 + (l & 15);
    const float swn = swv[n];
    const float bv = bias[n];
#pragma unroll
    for (int mi = 0; mi < 8; ++mi) {
      const int mbase = bm0 + wm * 128 + mi * 16 + (l >> 4) * 4;
#pragma unroll
      for (int r = 0; r < 4; ++r)
        C[(size_t)(mbase + r) * N_DIM + n] =
            (float)acc[mi][ni][r] * (swn * sxv[mbase + r]) + bv;
    }
  }
}

// ---------------- naive fallback ----------------

__global__ void naive_kernel(const float* __restrict__ x, const int* __restrict__ q,
                             const float* __restrict__ sc, const float* __restrict__ bias,
                             float* __restrict__ out) {
  size_t idx = (size_t)blockIdx.x * blockDim.x + threadIdx.x;
  if (idx >= (size_t)M_DIM * N_DIM) return;
  int n = (int)(idx & (N_DIM - 1));
  size_t m = idx >> 12;
  float acc = 0.f;
  for (int k = 0; k < K_DIM; k += 32) {
    float s = sc[n * NB_SC + (k >> 5)];
    float part = 0.f;
    for (int j = 0; j < 32; ++j)
      part += x[m * K_DIM + k + j] * (float)q[(size_t)n * K_DIM + k + j];
    acc += part * s;
  }
  out[idx] = acc + bias[n];
}

// ---------------- launch ----------------

extern "C" void kernel_launch(void* const* d_in, const int* in_sizes, int n_in,
                              void* d_out, int out_size, void* d_ws, size_t ws_size,
                              hipStream_t stream) {
  const float* x    = (const float*)d_in[0];
  const int*   q    = (const int*)d_in[1];
  const float* sc   = (const float*)d_in[2];
  const float* bias = (const float*)d_in[3];
  float* out = (float*)d_out;

  const size_t elems = (size_t)M_DIM * K_DIM;               // 16.8M
  const size_t need  = 2 * elems + 2 * 4096 * sizeof(float);  // ~32 MB + 32 KB

  if (ws_size >= need) {
    char* xb = (char*)d_ws;
    char* wb = xb + elems;
    float* sxv = (float*)(wb + elems);
    float* swv = sxv + 4096;
    hipLaunchKernelGGL(prep_kernel, dim3(8192), dim3(256), 0, stream,
                       x, q, sc, xb, wb, sxv, swv);
    hipLaunchKernelGGL(gemm256, dim3((M_DIM / BM) * (N_DIM / BN)), dim3(512), 0, stream,
                       xb, wb, sxv, swv, bias, out);
  } else {
    hipLaunchKernelGGL(naive_kernel, dim3((M_DIM * N_DIM) / 256), dim3(256), 0, stream,
                       x, q, sc, bias, out);
  }
}